// Round 7
// baseline (37.046 us; speedup 1.0000x reference)
//
#include <hip/hip_runtime.h>

#define NB 8
#define NT 1024
#define NK 8
#define NL 1024
#define NH 256
#define NE 128
#define NF 64
#define NV 23

typedef __attribute__((ext_vector_type(8))) short bf16x8;
typedef __attribute__((ext_vector_type(4))) float f32x4;

// one VALU op: packs 2 f32 -> 2 bf16 (RNE), lo = s0, hi = s1
__device__ __forceinline__ unsigned cvt_pk_bf16(float lo, float hi) {
  unsigned r;
  asm("v_cvt_pk_bf16_f32 %0, %1, %2" : "=v"(r) : "v"(lo), "v"(hi));
  return r;
}

__device__ __forceinline__ uint4 pack8(const float4 f0, const float4 f1) {
  uint4 u;
  u.x = cvt_pk_bf16(f0.x, f0.y);
  u.y = cvt_pk_bf16(f0.z, f0.w);
  u.z = cvt_pk_bf16(f1.x, f1.y);
  u.w = cvt_pk_bf16(f1.z, f1.w);
  return u;
}

// ---------------------------------------------------------------------------
// Prep: two pre-swizzled bf16 images of W1 slices (chunk = 8 k x 1 n, 16 B).
//  imgEx (4096 chunks): g in [0,16)  -> W1 rows 256+g*8..+7   (ex slice)
//  imgB (10240 chunks): g in [0,32)  -> W1 rows g*8..+7       (hs slice)
//                       g in [32,40) -> W1 rows 384+(g-32)*8  (col slice)
//  chunk address: g*256 + (n ^ (g&7)).
// ---------------------------------------------------------------------------
__global__ __launch_bounds__(64) void k_prep(const float* __restrict__ W1,
                                             uint4* __restrict__ imgEx,
                                             uint4* __restrict__ imgB) {
  const int c = blockIdx.x * 64 + threadIdx.x;  // 3584 slots of 4 chunks
  int g, n0, wrow0;
  uint4* img;
  if (c < 1024) {
    g = c >> 6; n0 = (c & 63) * 4;
    wrow0 = NH + g * 8;
    img = imgEx;
  } else {
    const int c2 = c - 1024;
    g = c2 >> 6; n0 = (c2 & 63) * 4;
    wrow0 = (g < 32) ? g * 8 : 384 + (g - 32) * 8;
    img = imgB;
  }
  float4 r[8];
#pragma unroll
  for (int j = 0; j < 8; ++j)
    r[j] = *(const float4*)&W1[(size_t)(wrow0 + j) * NH + n0];
  const float* rf = (const float*)r;  // rf[j*4 + d]
#pragma unroll
  for (int d = 0; d < 4; ++d) {
    uint4 u;
    u.x = cvt_pk_bf16(rf[0 * 4 + d], rf[1 * 4 + d]);
    u.y = cvt_pk_bf16(rf[2 * 4 + d], rf[3 * 4 + d]);
    u.z = cvt_pk_bf16(rf[4 * 4 + d], rf[5 * 4 + d]);
    u.w = cvt_pk_bf16(rf[6 * 4 + d], rf[7 * 4 + d]);
    img[g * 256 + ((n0 + d) ^ (g & 7))] = u;
  }
}

// ---- device helpers for the mega kernel ----

__device__ __forceinline__ void gather_issue(const float* __restrict__ ex,
                                             int b, int c, int lm, int lg,
                                             float4 (&pf)[8]) {
  const float* arow = &ex[(((size_t)b * NK + (lm & 7)) * NL + c) * NE];
#pragma unroll
  for (int ks = 0; ks < 4; ++ks) {
    const int g = ks * 4 + lg;
    pf[2 * ks] = *(const float4*)(arow + g * 8);
    pf[2 * ks + 1] = *(const float4*)(arow + g * 8 + 4);
  }
}

__device__ __forceinline__ void base_part(const float* __restrict__ hs,
                                          const float* __restrict__ col,
                                          const int* __restrict__ c_t,
                                          const uint4* __restrict__ imgB,
                                          const float* __restrict__ b1,
                                          int b, int t0, int w, int lm, int lg,
                                          uint4* __restrict__ Ub) {
  const int myt = t0 + lm;
  const int ctv = c_t[b * NT + myt];
  const int myc = ctv < 0 ? 0 : ctv;
  f32x4 accB[2];
#pragma unroll
  for (int f = 0; f < 2; ++f) {
    const float4 bv = *(const float4*)&b1[(w * 2 + f) * 16 + lg * 4];
    accB[f][0] = bv.x; accB[f][1] = bv.y; accB[f][2] = bv.z; accB[f][3] = bv.w;
  }
#pragma unroll
  for (int hb = 0; hb < 2; ++hb) {
    float4 f0a[5], f1a[5];
    uint4 bb[10];
#pragma unroll
    for (int i = 0; i < 5; ++i) {
      const int gk = (hb * 5 + i) * 4 + lg;  // 0..39
      const float* asrc = (gk < 32)
          ? &hs[((size_t)b * NT + myt) * NH + gk * 8]
          : &col[((size_t)b * NL + myc) * NF + (gk - 32) * 8];
      f0a[i] = *(const float4*)asrc;
      f1a[i] = *(const float4*)(asrc + 4);
    }
#pragma unroll
    for (int i = 0; i < 5; ++i) {
      const int gk = (hb * 5 + i) * 4 + lg;
#pragma unroll
      for (int f = 0; f < 2; ++f) {
        const int n = (w * 2 + f) * 16 + lm;
        bb[i * 2 + f] = imgB[(size_t)gk * 256 + (n ^ (gk & 7))];
      }
    }
#pragma unroll
    for (int i = 0; i < 5; ++i) {
      union { uint4 u; bf16x8 v; } A;
      A.u = pack8(f0a[i], f1a[i]);
#pragma unroll
      for (int f = 0; f < 2; ++f) {
        union { uint4 u; bf16x8 v; } B2;
        B2.u = bb[i * 2 + f];
        accB[f] = __builtin_amdgcn_mfma_f32_16x16x32_bf16(B2.v, A.v, accB[f], 0, 0, 0);
      }
    }
  }
#pragma unroll
  for (int f = 0; f < 2; ++f) {
    union { uint4 u; f32x4 v; } o;
    o.v = accB[f];
    Ub[lm * 64 + (((w * 2 + f) * 4 + lg) ^ lm)] = o.u;
  }
}

__device__ __forceinline__ void ex_mfma(const float4 (&pf)[8],
                                        const uint4* __restrict__ Bs,
                                        int w, int lm, int lg,
                                        f32x4 (&acc)[16]) {
#pragma unroll
  for (int ks = 0; ks < 4; ++ks) {
    const int g = ks * 4 + lg;
    union { uint4 u; bf16x8 v; } A;
    A.u = pack8(pf[2 * ks], pf[2 * ks + 1]);
#pragma unroll
    for (int fn = 0; fn < 16; ++fn) {
      const bf16x8 bfr = *(const bf16x8*)&Bs[g * 256 + ((fn * 16 + lm) ^ (g & 7))];
      acc[fn] = __builtin_amdgcn_mfma_f32_16x16x32_bf16(bfr, A.v, acc[fn], 0, 0, 0);
    }
  }
}

__device__ __forceinline__ void epilogue(f32x4 (&acc)[16],
                                         const uint4* __restrict__ Ub,
                                         const float* __restrict__ W2, float b2v,
                                         const int* __restrict__ aa_ids,
                                         int b, int t0, int w, int lane, int lm,
                                         int lg, bool valid, int c,
                                         float* __restrict__ p_copy,
                                         float* __restrict__ lam) {
  const int t_local = w * 2 + (lm >> 3);
  float p = 0.f;
#pragma unroll
  for (int fn = 0; fn < 16; ++fn) {
    const int n0 = fn * 16 + lg * 4;
    union { uint4 u; f32x4 v; } ubv;
    ubv.u = Ub[t_local * 64 + ((fn * 4 + lg) ^ t_local)];
    const float4 w2v = *(const float4*)&W2[n0];
    p += fmaxf(acc[fn][0] + ubv.v[0], 0.f) * w2v.x +
         fmaxf(acc[fn][1] + ubv.v[1], 0.f) * w2v.y +
         fmaxf(acc[fn][2] + ubv.v[2], 0.f) * w2v.z +
         fmaxf(acc[fn][3] + ubv.v[3], 0.f) * w2v.w;
  }
  p += __shfl_xor(p, 16);
  p += __shfl_xor(p, 32);
  const float score = p + b2v;

  float mx = score;
  mx = fmaxf(mx, __shfl_xor(mx, 1));
  mx = fmaxf(mx, __shfl_xor(mx, 2));
  mx = fmaxf(mx, __shfl_xor(mx, 4));
  const float e = __expf(score - mx);
  float s = e;
  s += __shfl_xor(s, 1);
  s += __shfl_xor(s, 2);
  s += __shfl_xor(s, 4);
  const float wgt = valid ? (e / s) : 0.f;

  if (lg == 0) lam[((size_t)b * NT + t0 + w * 2) * NK + lm] = wgt;

  int aav = 0;
  if (lg == 0) aav = aa_ids[((size_t)b * NK + (lm & 7)) * NL + c];

  const int bin = lane & 31;
  const int half = lane >> 5;
  const int src0 = half * 8;
  float pc = 0.f;
#pragma unroll
  for (int k = 0; k < 8; ++k) {
    const int a = __shfl(aav, src0 + k);
    const float ww = __shfl(wgt, src0 + k);
    pc += (a == bin) ? ww : 0.f;
  }
  if (bin < NV)
    p_copy[((size_t)b * NT + t0 + w * 2 + half) * NV + bin] = pc;
}

// ---------------------------------------------------------------------------
// Mega kernel, tile-paired persistent: grid = 256 (1 block/CU, 96 KB LDS),
// block (bid) -> batch b = bid&7 (XCD-affine: ex[b] becomes L2-resident),
// two 16-row t-tiles: t0A = (bid>>3)*32, t0B = t0A+16.
//   prologue: stage W1ex once; gather A (tileA); base(tileA)->Ub0; barrier
//   tileA: issue gather B; mfma(A); epilogue(A); base(tileB)->Ub1; barrier
//   tileB: mfma(B); epilogue(B)
// Tile-B's gather latency hides under mfma(A)+epilogue(A) (no intervening
// vmcnt(0) barrier until mid-barrier).
// ---------------------------------------------------------------------------
__global__ __launch_bounds__(512, 2) void k_mega(
    const float* __restrict__ hs, const float* __restrict__ ex,
    const float* __restrict__ col, const int* __restrict__ c_t,
    const int* __restrict__ aa_ids, const uint4* __restrict__ imgEx,
    const uint4* __restrict__ imgB, const float* __restrict__ b1,
    const float* __restrict__ W2, const float* __restrict__ b2,
    float* __restrict__ p_copy, float* __restrict__ lam) {
  extern __shared__ uint4 smem[];
  uint4* Bs = smem;           // 4096 chunks = 64 KB
  uint4* Ub0 = smem + 4096;   // 1024 chunks = 16 KB
  uint4* Ub1 = smem + 5120;   // 1024 chunks = 16 KB

  const int tid = threadIdx.x;
  const int lane = tid & 63;
  const int w = tid >> 6;
  const int lm = lane & 15;
  const int lg = lane >> 4;
  const int bid = blockIdx.x;
  const int b = bid & 7;            // XCD-affine batch
  const int t0A = (bid >> 3) * 32;
  const int t0B = t0A + 16;

  // ---- prologue ----
#pragma unroll
  for (int it = 0; it < 8; ++it) {
    const int off = (w * 8 + it) * 64;
    __builtin_amdgcn_global_load_lds(
        (const __attribute__((address_space(1))) void*)(imgEx + off + lane),
        (__attribute__((address_space(3))) void*)(Bs + off), 16, 0, 0);
  }

  const int t_local = w * 2 + (lm >> 3);
  const int ctA = c_t[b * NT + t0A + t_local];
  const bool validA = ctA >= 0;
  const int cA = validA ? ctA : 0;
  const int ctB = c_t[b * NT + t0B + t_local];
  const bool validB = ctB >= 0;
  const int cB = validB ? ctB : 0;

  float4 pf0[8];
  gather_issue(ex, b, cA, lm, lg, pf0);

  base_part(hs, col, c_t, imgB, b1, b, t0A, w, lm, lg, Ub0);

  const float b2v = b2[0];
  __syncthreads();

  // ---- tile A ----
  float4 pf1[8];
  gather_issue(ex, b, cB, lm, lg, pf1);  // in flight across tile A

  f32x4 acc[16] = {};
  ex_mfma(pf0, Bs, w, lm, lg, acc);
  epilogue(acc, Ub0, W2, b2v, aa_ids, b, t0A, w, lane, lm, lg, validA, cA,
           p_copy, lam);

  base_part(hs, col, c_t, imgB, b1, b, t0B, w, lm, lg, Ub1);
  __syncthreads();

  // ---- tile B ----
  f32x4 acc2[16] = {};
  ex_mfma(pf1, Bs, w, lm, lg, acc2);
  epilogue(acc2, Ub1, W2, b2v, aa_ids, b, t0B, w, lane, lm, lg, validB, cB,
           p_copy, lam);
}

extern "C" void kernel_launch(void* const* d_in, const int* in_sizes, int n_in,
                              void* d_out, int out_size, void* d_ws, size_t ws_size,
                              hipStream_t stream) {
  const float* hs = (const float*)d_in[0];
  const float* ex = (const float*)d_in[1];
  const float* col = (const float*)d_in[2];
  const int* ct = (const int*)d_in[3];
  const int* aa = (const int*)d_in[4];
  const float* W1 = (const float*)d_in[5];
  const float* b1 = (const float*)d_in[6];
  const float* W2 = (const float*)d_in[7];
  const float* b2 = (const float*)d_in[8];

  uint4* imgEx = (uint4*)d_ws;        // 64 KB
  uint4* imgB = imgEx + 4096;         // 160 KB

  float* p_copy = (float*)d_out;
  float* lam = p_copy + (size_t)NB * NT * NV;

  const size_t lds_bytes = (4096 + 2048) * sizeof(uint4);  // 96 KB

  k_prep<<<56, 64, 0, stream>>>(W1, imgEx, imgB);
  k_mega<<<256, 512, lds_bytes, stream>>>(hs, ex, col, ct, aa, imgEx, imgB,
                                          b1, W2, b2, p_copy, lam);
}